// Round 15
// baseline (26.061 us; speedup 1.0000x reference)
//
#include <hip/hip_runtime.h>

#define NS 128
#define NX 512
#define NY 512
#define NT 2048
#define WIN 64          // per-sensor LDS window (pow2)
#define TI 16           // tile rows
#define TJ 16           // tile cols

// ===== NUMERICS CONTRACT (R2/R4/R10/R12 failed; R0/R3/R5-R9/R11/R13/R14) ===
// floor(idx) must match the np reference everywhere; idx recipe, SCALAR ONLY:
//     d2   = dx*dx + dy*dy;                 // EXACT SOURCE TEXT, scalar
//     dist = sqrt_cr(d2);                   // proven bit-exact R7-R9,R11,R13,R14
//     idx  = dist * (1.0f/1500.0f) * (1.0f/4e-08f);  // two separate RN muls
// fract/trunc proven safe (R7+). FORBIDDEN (each failed a round):
//   - folded scale inside sqrt (R2); raw 1-ulp v_sqrt for idx (R2)
//   - ANY float2/packed math on the idx path (R4+R12, identical 4.494141
//     fingerprint); changing the d2 expression text (R4)
// Window coverage (WIN=64, ref px (8,8) of 16x16 tile): |Δ| <= 14.77
// samples; ws=(int)idxc-31 -> slot e in [15,47], e+1 <= 48 < 64.
//
// R15 THEORY: R8..R14 all sit at 24.5us = T_VALU(9.8) + T_gatherpipe(14.9):
// the per-CU gather pipe (DS for LDS variants, TA/L1 for R8) serializes
// against VALU. This kernel SPLITS gathers across BOTH pipes: pixel0 reads
// the LDS window (DS), pixel1 reads global x via L1 (TA). Values are
// bit-identical either way; numerics DAG untouched.

__device__ __forceinline__ float sqrt_cr(float x) {
    const float r0 = __builtin_amdgcn_sqrtf(x);               // <=1 ulp
    const float rd = __int_as_float(__float_as_int(r0) - 1);
    const float ru = __int_as_float(__float_as_int(r0) + 1);
    const float vd = fmaf(-rd, r0, x);
    const float vu = fmaf(-ru, r0, x);
    float r = (vd <= 0.0f) ? rd : r0;
    r = (vu > 0.0f) ? ru : r;
    return r;
}

__global__ __launch_bounds__(512, 8) void das_kernel(
        const float* __restrict__ x,        // (NS, NT)
        const float* __restrict__ sensors,  // (NS, 2)
        const float* __restrict__ grid,     // (P, 2)
        float* __restrict__ out) {          // (P,)
    __shared__ float4 rec[NS];              // {sx, sy, ldsoff bits, gbase bits}
    __shared__ float win[NS * WIN];         // 32 KB sample windows
    __shared__ float part[2][512];

    const int tid = threadIdx.x;
    const int bi = blockIdx.x;              // 1024 blocks
    const int ti = bi >> 5;                 // 0..31
    const int tj = bi & 31;                 // 0..31

    // --- phase 1: per-sensor record from tile reference pixel (8,8)
    if (tid < NS) {
        const float2 sv = reinterpret_cast<const float2*>(sensors)[tid];
        const float2 gc = reinterpret_cast<const float2*>(
            grid)[(ti * TI + 8) * NY + (tj * TJ + 8)];
        const float dx = gc.x - sv.x;
        const float dy = gc.y - sv.y;
        const float idxc = __builtin_amdgcn_sqrtf(dx * dx + dy * dy)
                           * (1.0f / 1500.0f) * (1.0f / 4e-08f);
        const int ws = (int)idxc - 31;      // window covers ws .. ws+63
        rec[tid] = make_float4(sv.x, sv.y,
                               __int_as_float(tid * WIN - ws),
                               __int_as_float(tid * NT + ws));
    }
    __syncthreads();

    // --- phase 2: stage windows; each of 8 waves stages one sensor/round
    const int wv = tid >> 6;
    const int lane = tid & 63;
#pragma unroll
    for (int r = 0; r < NS / 8; ++r) {
        const int s = r * 8 + wv;
        const int gb = __float_as_int(rec[s].w);   // uniform LDS broadcast
        win[s * WIN + lane] = x[gb + lane];        // 256B coalesced row copy
    }
    __syncthreads();

    // --- main loop: 2 pixels/lane; px0 gathers via DS pipe (LDS window),
    // px1 gathers via TA/L1 pipe (global x, SGPR row base + voffset)
    const int quad = tid >> 7;              // sensor quarter
    const int pl = tid & 127;               // px0 in tile (rows 0..7)
    const int p0 = (ti * TI + (pl >> 4)) * NY + (tj * TJ + (pl & 15));
    const int p1 = p0 + 8 * NY;             // px1 = px0 + 8 rows

    const float2 g0 = reinterpret_cast<const float2*>(grid)[p0];
    const float2 g1 = reinterpret_cast<const float2*>(grid)[p1];

    const float inv_c = 1.0f / 1500.0f;
    const float inv_dt = 1.0f / 4e-08f;

    const int sbase = __builtin_amdgcn_readfirstlane(quad << 5);
    const float4* recp = rec + sbase;
    const float* xq = x + sbase * NT;       // SGPR base for px1 global gathers

    float accA0 = 0.0f, accB0 = 0.0f;       // scalar chains only
    float accA1 = 0.0f, accB1 = 0.0f;
#pragma unroll
    for (int s = 0; s < 32; ++s) {
        const float4 rc = recp[s];                 // ds_read_b128, uniform
        const float svx = rc.x;
        const float svy = rc.y;
        const int o = __float_as_int(rc.z);        // window element offset

        // FROZEN SCALAR DAG, pixel 0 (R14 text)
        const float dx0 = g0.x - svx;
        const float dy0 = g0.y - svy;
        const float dist0 = sqrt_cr(dx0 * dx0 + dy0 * dy0);
        const float idx0 = dist0 * inv_c * inv_dt;
        const int i00 = (int)idx0;                 // trunc == floor
        const float w00 = __builtin_amdgcn_fractf(idx0);

        // FROZEN SCALAR DAG, pixel 1
        const float dx1 = g1.x - svx;
        const float dy1 = g1.y - svy;
        const float dist1 = sqrt_cr(dx1 * dx1 + dy1 * dy1);
        const float idx1 = dist1 * inv_c * inv_dt;
        const int i10 = (int)idx1;
        const float w10 = __builtin_amdgcn_fractf(idx1);

        // px0: DS pipe (staged window, bit-identical to x)
        const float* wp0 = &win[i00 + o];
        const float y00 = wp0[0];                  // ds_read2_b32
        const float y01 = wp0[1];

        // px1: TA/L1 pipe (global, 1MB signal is L1/L2-resident)
        const float* rp1 = xq + s * NT;            // SGPR base per sensor
        const float y10 = rp1[i10];                // global_load_dword
        const float y11 = rp1[i10 + 1];            // offset:4 fold

        accA0 = fmaf(w00, y00 - y01, accA0);  accB0 += y01;
        accA1 = fmaf(w10, y10 - y11, accA1);  accB1 += y11;
    }

    part[0][tid] = accA0 + accB0;           // px0 partial
    part[1][tid] = accA1 + accB1;           // px1 partial
    __syncthreads();
    if (tid < 256) {
        const int t = tid;                  // pixel in 16x16 tile
        const int c = t >> 7;               // 0: rows 0-7, 1: rows 8-15
        const int q = t & 127;
        const float v = part[c][q] + part[c][q + 128]
                      + part[c][q + 256] + part[c][q + 384];
        out[(ti * TI + (t >> 4)) * NY + (tj * TJ + (t & 15))] = v;
    }
}

extern "C" void kernel_launch(void* const* d_in, const int* in_sizes, int n_in,
                              void* d_out, int out_size, void* d_ws, size_t ws_size,
                              hipStream_t stream) {
    const float* x = (const float*)d_in[0];        // (1, NS, NT)
    const float* sensors = (const float*)d_in[1];  // (NS, 2)
    const float* grid = (const float*)d_in[2];     // (P, 2)
    float* out = (float*)d_out;                    // (1, NX, NY)

    const int nblocks = (NX / TI) * (NY / TJ);     // 1024 blocks, 512 threads
    das_kernel<<<nblocks, 512, 0, stream>>>(x, sensors, grid, out);
}